// Round 15
// baseline (202.072 us; speedup 1.0000x reference)
//
#include <hip/hip_runtime.h>
#include <hip/hip_bf16.h>
#include <math.h>

#define N_NODES 10000
#define N_EDGES 160000
#define EB 16

typedef unsigned short ushort_t;
using f32x4 = __attribute__((ext_vector_type(4))) float;
using s16x8 = __attribute__((ext_vector_type(8))) short;

__device__ __forceinline__ float sigmoidf_(float x){ return 1.f/(1.f+__expf(-x)); }
__device__ __forceinline__ ushort_t f2bf(float x){
  __hip_bfloat16 h = __float2bfloat16(x);
  return *reinterpret_cast<ushort_t*>(&h);
}
__device__ __forceinline__ float bf2f(ushort_t u){
  unsigned int v = ((unsigned int)u)<<16;
  return __uint_as_float(v);
}
__device__ __forceinline__ ushort_t tbf(float x){
  return (ushort_t)(__float_as_uint(x) >> 16);
}
__device__ __forceinline__ void split_t(float x, ushort_t &hi, ushort_t &lo){
  unsigned xb = __float_as_uint(x);
  hi = (ushort_t)(xb >> 16);
  float l = x - __uint_as_float(xb & 0xFFFF0000u);
  lo = (ushort_t)(__float_as_uint(l) >> 16);
}
#define PSEL 0x07060302u
__device__ __forceinline__ unsigned pack2t(float x0, float x1){
  return __builtin_amdgcn_perm(__float_as_uint(x1), __float_as_uint(x0), PSEL);
}
union SplitU { uint4 u; s16x8 v; };
__device__ __forceinline__ void build_split8(const float* __restrict__ src, s16x8 &ah, s16x8 &al){
  float4 xa = *(const float4*)&src[0];
  float4 xb = *(const float4*)&src[4];
  float x[8] = {xa.x,xa.y,xa.z,xa.w,xb.x,xb.y,xb.z,xb.w};
  SplitU H, L;
  #pragma unroll
  for (int p=0;p<4;p++){
    unsigned b0 = __float_as_uint(x[2*p]), b1 = __float_as_uint(x[2*p+1]);
    ((unsigned*)&H.u)[p] = __builtin_amdgcn_perm(b1, b0, PSEL);
    float l0 = x[2*p]   - __uint_as_float(b0 & 0xFFFF0000u);
    float l1 = x[2*p+1] - __uint_as_float(b1 & 0xFFFF0000u);
    ((unsigned*)&L.u)[p] = __builtin_amdgcn_perm(__float_as_uint(l1), __float_as_uint(l0), PSEL);
  }
  ah = H.v; al = L.v;
}

// ---- packed-weight ushort offsets (in pk) ----
#define PK_RW1H  0
#define PK_RW1L  4096
#define PK_RW2H  8192
#define PK_RW2L  12288
#define PK_RW3AH 16384
#define PK_RW3AL 28672
#define PK_RW3P  40960
#define PK_LW0AH 57344
#define PK_LW0AL 63488
#define PK_LW0P  69632
#define PK_LW1P  94208
#define PK_PW0H  110592
#define PK_PW0L  126976
#define PK_PW1H  143360
#define PK_PW1L  147456
#define PK_NS0H  151552
#define PK_NS0L  167936
#define PK_ND0H  184320
#define PK_ND0L  200704
#define PK_NS1H  217088
#define PK_NS1L  221184
#define PK_ND1H  225280
#define PK_ND1L  229376
#define PK_TOTAL 233472

// ---------------- k_pack (unchanged) ----------------
__global__ __launch_bounds__(256) void k_pack(
  const float* __restrict__ rw1, const float* __restrict__ rw2,
  const float* __restrict__ rw3, const float* __restrict__ lw0,
  const float* __restrict__ lw1, const float* __restrict__ pw0,
  const float* __restrict__ pw1,
  const float* __restrict__ w_src0, const float* __restrict__ w_dst0,
  const float* __restrict__ w_src1, const float* __restrict__ w_dst1,
  ushort_t* __restrict__ pk)
{
  int idx = blockIdx.x*256 + threadIdx.x;
  if (idx < 4096){
    int nt=idx>>10, r=idx&1023, kt=r>>9, q=r&511, l=q>>3, i=q&7;
    int k = kt*32 + (l>>4)*8 + i, col = nt*16 + (l&15);
    float x = rw1[k*64 + col];
    ushort_t hi = f2bf(x);
    pk[PK_RW1H+idx] = hi; pk[PK_RW1L+idx] = f2bf(x - bf2f(hi));
  } else if (idx < 8192){
    int j = idx-4096;
    int nt=j>>10, r=j&1023, kt=r>>9, q=r&511, l=q>>3, i=q&7;
    int k = kt*32 + (l>>4)*8 + i, col = nt*16 + (l&15);
    float x = rw2[k*64 + col];
    ushort_t hi = f2bf(x);
    pk[PK_RW2H+j] = hi; pk[PK_RW2L+j] = f2bf(x - bf2f(hi));
  } else if (idx < 20480){
    int j = idx-8192;
    int nt=j>>10, r=j&1023, kt=r>>9, q=r&511, l=q>>3, i=q&7;
    int k = kt*32 + (l>>4)*8 + i;
    int col = (nt<8) ? nt*16+(l&15) : 320+(nt-8)*16+(l&15);
    float x = rw3[(size_t)k*448 + col];
    ushort_t hi = f2bf(x);
    pk[PK_RW3AH+j] = hi; pk[PK_RW3AL+j] = f2bf(x - bf2f(hi));
  } else if (idx < 36864){
    int j = idx-20480;
    int nt=j>>10, r=j&1023, kt=r>>9, q=r&511, l=q>>3, i=q&7;
    int k = kt*32 + (l>>4)*8 + i;
    int v = nt*16 + (l&15);
    int col = (v<128) ? 128+v : (v<192) ? 256+(v-128) : 384+(v-192);
    pk[PK_RW3P+j] = f2bf(rw3[(size_t)k*448 + col]);
  } else if (idx < 43008){
    int j = idx-36864;
    int nt=j/3072, r=j-nt*3072, kt=r>>9, q=r&511, l=q>>3, i=q&7;
    int k = kt*32 + (l>>4)*8 + i;
    int qq = nt*16 + (l&15);
    int col = (qq>>3)*40 + (qq&7);
    float x = lw0[(size_t)k*160 + col];
    ushort_t hi = f2bf(x);
    pk[PK_LW0AH+j] = hi; pk[PK_LW0AL+j] = f2bf(x - bf2f(hi));
  } else if (idx < 67584){
    int j = idx-43008;
    int nt=j/3072, r=j-nt*3072, kt=r>>9, q=r&511, l=q>>3, i=q&7;
    int k = kt*32 + (l>>4)*8 + i;
    int v = nt*16 + (l&15);
    int col = (v>>5)*40 + 8 + (v&31);
    pk[PK_LW0P+j] = f2bf(lw0[(size_t)k*160 + col]);
  } else if (idx < 83968){
    int j = idx-67584;
    int nt=j>>12, r=j&4095, kt=r>>9, q=r&511, l=q>>3, i=q&7;
    int k = kt*32 + (l>>4)*8 + i, col = nt*16 + (l&15);
    pk[PK_LW1P+j] = f2bf(lw1[(size_t)k*64 + col]);
  } else if (idx < 100352){
    int j = idx-83968;
    int nt=j>>11, r=j&2047, kt=r>>9, q=r&511, l=q>>3, i=q&7;
    int k = kt*32 + (l>>4)*8 + i, col = nt*16 + (l&15);
    float x = pw0[k*128 + col];
    ushort_t hi = f2bf(x);
    pk[PK_PW0H+j] = hi; pk[PK_PW0L+j] = f2bf(x - bf2f(hi));
  } else if (idx < 104448){
    int j = idx-100352;
    int nt=j>>10, r=j&1023, kt=r>>9, q=r&511, l=q>>3, i=q&7;
    int k = kt*32 + (l>>4)*8 + i, col = nt*16 + (l&15);
    float x = pw1[k*64 + col];
    ushort_t hi = f2bf(x);
    pk[PK_PW1H+j] = hi; pk[PK_PW1L+j] = f2bf(x - bf2f(hi));
  } else if (idx < 120832){
    int j = idx-104448;
    int nt=j>>11, r=j&2047, kt=r>>9, q=r&511, l=q>>3, i=q&7;
    int k = kt*32 + (l>>4)*8 + i, col = nt*16 + (l&15);
    float x = w_src0[k*128 + col];
    ushort_t hi = f2bf(x);
    pk[PK_NS0H+j] = hi; pk[PK_NS0L+j] = f2bf(x - bf2f(hi));
  } else if (idx < 137216){
    int j = idx-120832;
    int nt=j>>11, r=j&2047, kt=r>>9, q=r&511, l=q>>3, i=q&7;
    int k = kt*32 + (l>>4)*8 + i, col = nt*16 + (l&15);
    float x = w_dst0[k*128 + col];
    ushort_t hi = f2bf(x);
    pk[PK_ND0H+j] = hi; pk[PK_ND0L+j] = f2bf(x - bf2f(hi));
  } else if (idx < 141312){
    int j = idx-137216;
    int nt=j>>10, r=j&1023, kt=r>>9, q=r&511, l=q>>3, i=q&7;
    int k = kt*32 + (l>>4)*8 + i, col = nt*16 + (l&15);
    float x = w_src1[k*64 + col];
    ushort_t hi = f2bf(x);
    pk[PK_NS1H+j] = hi; pk[PK_NS1L+j] = f2bf(x - bf2f(hi));
  } else if (idx < 145408){
    int j = idx-141312;
    int nt=j>>10, r=j&1023, kt=r>>9, q=r&511, l=q>>3, i=q&7;
    int k = kt*32 + (l>>4)*8 + i, col = nt*16 + (l&15);
    float x = w_dst1[k*64 + col];
    ushort_t hi = f2bf(x);
    pk[PK_ND1H+j] = hi; pk[PK_ND1L+j] = f2bf(x - bf2f(hi));
  }
}

#define MFMA(a,b,c) __builtin_amdgcn_mfma_f32_16x16x32_bf16((a),(b),(c),0,0,0)

// ---------------- k_node2 (unchanged) ----------------
__global__ __launch_bounds__(256) void k_node2(
  const float* __restrict__ node_input,
  const float* __restrict__ b_src0, const float* __restrict__ b_dst0,
  const ushort_t* __restrict__ pk,
  float* __restrict__ ns_src, float* __restrict__ ns_dst,
  float* __restrict__ nv_src, float* __restrict__ nv_dst)
{
  __shared__ __align__(16) float S[16*132 + 3*16*68];
  const int t = threadIdx.x, n0 = blockIdx.x*16;
  const int lane = t&63, w = t>>6, arow = lane&15, kg = lane>>4, c16 = lane&15;
  {
    int n = t>>4, l = t&15;
    const float* row = &node_input[(size_t)(n0+n)*320];
    *(float4*)&S[n*132 + l*8 + 0] = *(const float4*)&row[l*8];
    *(float4*)&S[n*132 + l*8 + 4] = *(const float4*)&row[l*8+4];
    float f[12];
    #pragma unroll
    for (int j=0;j<3;j++){
      float4 a = *(const float4*)&row[128 + l*12 + j*4];
      f[j*4+0]=a.x; f[j*4+1]=a.y; f[j*4+2]=a.z; f[j*4+3]=a.w;
    }
    #pragma unroll
    for (int c=0;c<3;c++){
      float4 r; r.x=f[c]; r.y=f[3+c]; r.z=f[6+c]; r.w=f[9+c];
      *(float4*)&S[2112 + c*1088 + n*68 + l*4] = r;
    }
  }
  __syncthreads();
  const float rs128 = 0.08838834764831845f;
  {
    s16x8 ah[4], al[4];
    #pragma unroll
    for (int kt=0;kt<4;kt++)
      build_split8(&S[arow*132 + kt*32 + kg*8], ah[kt], al[kt]);
    #pragma unroll
    for (int q2=0;q2<4;q2++){
      int task = w*4+q2;
      int m = task>>3, nt = task&7;
      f32x4 acc = {0.f,0.f,0.f,0.f};
      #pragma unroll
      for (int kt=0;kt<4;kt++){
        s16x8 bh = *(const s16x8*)&pk[(m?PK_ND0H:PK_NS0H) + (size_t)((nt*4+kt)*64+lane)*8];
        s16x8 bl = *(const s16x8*)&pk[(m?PK_ND0L:PK_NS0L) + (size_t)((nt*4+kt)*64+lane)*8];
        acc = MFMA(ah[kt],bh,acc); acc = MFMA(ah[kt],bl,acc); acc = MFMA(al[kt],bh,acc);
      }
      int col = nt*16 + c16;
      float bv = (m ? b_dst0 : b_src0)[col];
      float* outp = m ? ns_dst : ns_src;
      #pragma unroll
      for (int r=0;r<4;r++)
        outp[(size_t)(n0 + kg*4 + r)*128 + col] = acc[r]*rs128 + bv;
    }
  }
  #pragma unroll
  for (int c=0;c<3;c++){
    s16x8 vah[2], vav[2];
    #pragma unroll
    for (int kt=0;kt<2;kt++)
      build_split8(&S[2112 + c*1088 + arow*68 + kt*32 + kg*8], vah[kt], vav[kt]);
    #pragma unroll
    for (int q2=0;q2<2;q2++){
      int task = w*2+q2;
      int m = task>>2, nt = task&3;
      f32x4 acc = {0.f,0.f,0.f,0.f};
      #pragma unroll
      for (int kt=0;kt<2;kt++){
        s16x8 bh = *(const s16x8*)&pk[(m?PK_ND1H:PK_NS1H) + (size_t)((nt*2+kt)*64+lane)*8];
        s16x8 bl = *(const s16x8*)&pk[(m?PK_ND1L:PK_NS1L) + (size_t)((nt*2+kt)*64+lane)*8];
        acc = MFMA(vah[kt],bh,acc); acc = MFMA(vah[kt],bl,acc); acc = MFMA(vav[kt],bh,acc);
      }
      int col = nt*16 + c16;
      float* outp = m ? nv_dst : nv_src;
      #pragma unroll
      for (int r=0;r<4;r++)
        outp[(size_t)(n0 + kg*4 + r)*192 + col*3 + c] = acc[r]*0.125f;
    }
  }
}

// ---------------- Kernel C: prefetch + setprio + val-path pipeline ----------------
#define OEA   0
#define OMV   64
#define OMS   3328
#define FX    5440
#define ESHI_US  (FX*2)
#define ESLO_US  (FX*2+1152)
#define D0HI_US  (FX*2)
#define D0LO_US  (FX*2+3200)
#define D1_US    (FX*2)
#define FY    8704
#define H1HI_US  (FY*2)
#define H1LO_US  (FY*2+1152)
#define ASV_US   (FY*2)
#define FH2   9856
#define H2HI_US  (FH2*2)
#define H2LO_US  (FH2*2+1152)
#define OBVS  11008
#define OWV1  12096

__global__ __launch_bounds__(256) void k_edge10(
  const float* __restrict__ edge_attr, const float* __restrict__ edge_scalars,
  const int* __restrict__ edge_src, const int* __restrict__ edge_dst,
  const float* __restrict__ ns_src, const float* __restrict__ ns_dst,
  const float* __restrict__ nv_src, const float* __restrict__ nv_dst,
  const float* __restrict__ rb1, const float* __restrict__ rb2,
  const float* __restrict__ rb3, const float* __restrict__ lb0,
  const float* __restrict__ alpha_dot,
  const ushort_t* __restrict__ pk,
  float* __restrict__ galpha, __hip_bfloat16* __restrict__ gval,
  __hip_bfloat16* __restrict__ gm1)
{
  __shared__ __align__(16) float L[13184];
  ushort_t* LU = (ushort_t*)L;
  const int t = threadIdx.x;
  const int e0 = blockIdx.x * EB;
  const int lane = t & 63, w = t >> 6;
  const int arow = lane & 15, kg = lane >> 4, c16 = lane & 15;

  // ---- PREFETCH P1 B-fragments ----
  s16x8 p1bh0 = *(const s16x8*)&pk[PK_RW1H + (size_t)((w*2+0)*64+lane)*8];
  s16x8 p1bl0 = *(const s16x8*)&pk[PK_RW1L + (size_t)((w*2+0)*64+lane)*8];
  s16x8 p1bh1 = *(const s16x8*)&pk[PK_RW1H + (size_t)((w*2+1)*64+lane)*8];
  s16x8 p1bl1 = *(const s16x8*)&pk[PK_RW1L + (size_t)((w*2+1)*64+lane)*8];

  // ---- P0 ----
  {
    int e = t>>4, l = t&15;
    int s = edge_src[e0+e], d = edge_dst[e0+e];
    #pragma unroll
    for (int j=0;j<2;j++){
      int idx = l + 16*j;
      float4 a = *(const float4*)&ns_src[(size_t)s*128 + idx*4];
      float4 b = *(const float4*)&ns_dst[(size_t)d*128 + idx*4];
      float4 r; r.x=a.x+b.x; r.y=a.y+b.y; r.z=a.z+b.z; r.w=a.w+b.w;
      *(float4*)&L[OMS + e*132 + idx*4] = r;
    }
    float f[12];
    #pragma unroll
    for (int j=0;j<3;j++){
      float4 a = *(const float4*)&nv_src[(size_t)s*192 + l*12 + j*4];
      float4 b = *(const float4*)&nv_dst[(size_t)d*192 + l*12 + j*4];
      f[j*4+0]=a.x+b.x; f[j*4+1]=a.y+b.y; f[j*4+2]=a.z+b.z; f[j*4+3]=a.w+b.w;
    }
    #pragma unroll
    for (int c=0;c<3;c++){
      float4 r; r.x=f[c]; r.y=f[3+c]; r.z=f[6+c]; r.w=f[9+c];
      *(float4*)&L[OMV + e*204 + c*68 + l*4] = r;
    }
    float4 x = *(const float4*)&edge_scalars[(size_t)(e0+e)*64 + l*4];
    unsigned b0=__float_as_uint(x.x), b1=__float_as_uint(x.y), b2=__float_as_uint(x.z), b3=__float_as_uint(x.w);
    uint2 hi2, lo2;
    hi2.x = __builtin_amdgcn_perm(b1, b0, PSEL);
    hi2.y = __builtin_amdgcn_perm(b3, b2, PSEL);
    float l0 = x.x - __uint_as_float(b0 & 0xFFFF0000u);
    float l1 = x.y - __uint_as_float(b1 & 0xFFFF0000u);
    float l2 = x.z - __uint_as_float(b2 & 0xFFFF0000u);
    float l3 = x.w - __uint_as_float(b3 & 0xFFFF0000u);
    lo2.x = pack2t(l0, l1);
    lo2.y = pack2t(l2, l3);
    *(uint2*)&LU[ESHI_US + e*72 + l*4] = hi2;
    *(uint2*)&LU[ESLO_US + e*72 + l*4] = lo2;
  }
  if (t < 64) L[OEA + t] = edge_attr[(size_t)e0*4 + t];
  __syncthreads();

  // ---- P1 (prefetch P2) ----
  s16x8 p2bh0 = *(const s16x8*)&pk[PK_RW2H + (size_t)((w*2+0)*64+lane)*8];
  s16x8 p2bl0 = *(const s16x8*)&pk[PK_RW2L + (size_t)((w*2+0)*64+lane)*8];
  s16x8 p2bh1 = *(const s16x8*)&pk[PK_RW2H + (size_t)((w*2+1)*64+lane)*8];
  s16x8 p2bl1 = *(const s16x8*)&pk[PK_RW2L + (size_t)((w*2+1)*64+lane)*8];
  {
    s16x8 ah0 = *(const s16x8*)&LU[ESHI_US + arow*72 + 0  + kg*8];
    s16x8 ah1 = *(const s16x8*)&LU[ESHI_US + arow*72 + 32 + kg*8];
    s16x8 al0 = *(const s16x8*)&LU[ESLO_US + arow*72 + 0  + kg*8];
    s16x8 al1 = *(const s16x8*)&LU[ESLO_US + arow*72 + 32 + kg*8];
    f32x4 acc = {0.f,0.f,0.f,0.f};
    __builtin_amdgcn_s_setprio(1);
    acc = MFMA(ah0,p1bh0,acc); acc = MFMA(ah0,p1bl0,acc); acc = MFMA(al0,p1bh0,acc);
    acc = MFMA(ah1,p1bh1,acc); acc = MFMA(ah1,p1bl1,acc); acc = MFMA(al1,p1bh1,acc);
    __builtin_amdgcn_s_setprio(0);
    int col = w*16 + c16;
    float rb = rb1[col];
    #pragma unroll
    for (int r=0;r<4;r++){
      int er = kg*4 + r;
      float v = acc[r] + rb;
      float h = v*sigmoidf_(v);
      ushort_t hi, lo; split_t(h, hi, lo);
      LU[H1HI_US + er*72 + col] = hi;
      LU[H1LO_US + er*72 + col] = lo;
    }
  }
  __syncthreads();

  // ---- P2 (prefetch P3 alpha tiles) ----
  s16x8 p3h0[3], p3l0[3], p3h1[3], p3l1[3];
  #pragma unroll
  for (int ai=0; ai<3; ai++){
    int a = w*3 + ai;
    p3h0[ai] = *(const s16x8*)&pk[PK_RW3AH + (size_t)((a*2+0)*64+lane)*8];
    p3l0[ai] = *(const s16x8*)&pk[PK_RW3AL + (size_t)((a*2+0)*64+lane)*8];
    p3h1[ai] = *(const s16x8*)&pk[PK_RW3AH + (size_t)((a*2+1)*64+lane)*8];
    p3l1[ai] = *(const s16x8*)&pk[PK_RW3AL + (size_t)((a*2+1)*64+lane)*8];
  }
  {
    s16x8 ah0 = *(const s16x8*)&LU[H1HI_US + arow*72 + 0  + kg*8];
    s16x8 ah1 = *(const s16x8*)&LU[H1HI_US + arow*72 + 32 + kg*8];
    s16x8 al0 = *(const s16x8*)&LU[H1LO_US + arow*72 + 0  + kg*8];
    s16x8 al1 = *(const s16x8*)&LU[H1LO_US + arow*72 + 32 + kg*8];
    f32x4 acc = {0.f,0.f,0.f,0.f};
    __builtin_amdgcn_s_setprio(1);
    acc = MFMA(ah0,p2bh0,acc); acc = MFMA(ah0,p2bl0,acc); acc = MFMA(al0,p2bh0,acc);
    acc = MFMA(ah1,p2bh1,acc); acc = MFMA(ah1,p2bl1,acc); acc = MFMA(al1,p2bh1,acc);
    __builtin_amdgcn_s_setprio(0);
    int col = w*16 + c16;
    float rb = rb2[col];
    #pragma unroll
    for (int r=0;r<4;r++){
      int er = kg*4 + r;
      float v = acc[r] + rb;
      float h = v*sigmoidf_(v);
      ushort_t hi, lo; split_t(h, hi, lo);
      LU[H2HI_US + er*72 + col] = hi;
      LU[H2LO_US + er*72 + col] = lo;
    }
  }
  __syncthreads();

  // ---- P3 ----
  {
    s16x8 pp0[4], pp1[4];
    #pragma unroll
    for (int pi=0; pi<4; pi++){
      int p = w*4 + pi;
      pp0[pi] = *(const s16x8*)&pk[PK_RW3P + (size_t)((p*2+0)*64+lane)*8];
      pp1[pi] = *(const s16x8*)&pk[PK_RW3P + (size_t)((p*2+1)*64+lane)*8];
    }
    s16x8 ah0 = *(const s16x8*)&LU[H2HI_US + arow*72 + 0  + kg*8];
    s16x8 ah1 = *(const s16x8*)&LU[H2HI_US + arow*72 + 32 + kg*8];
    s16x8 al0 = *(const s16x8*)&LU[H2LO_US + arow*72 + 0  + kg*8];
    s16x8 al1 = *(const s16x8*)&LU[H2LO_US + arow*72 + 32 + kg*8];

    #pragma unroll
    for (int ai=0; ai<3; ai++){
      int a = w*3 + ai;
      f32x4 acc = {0.f,0.f,0.f,0.f};
      __builtin_amdgcn_s_setprio(1);
      acc = MFMA(ah0,p3h0[ai],acc); acc = MFMA(ah0,p3l0[ai],acc); acc = MFMA(al0,p3h0[ai],acc);
      acc = MFMA(ah1,p3h1[ai],acc); acc = MFMA(ah1,p3l1[ai],acc); acc = MFMA(al1,p3h1[ai],acc);
      __builtin_amdgcn_s_setprio(0);
      if (a < 8){
        int i = a*16 + c16;
        float b3 = rb3[i];
        #pragma unroll
        for (int r=0;r<4;r++){
          int er = kg*4 + r;
          float d0v = (acc[r]+b3) * L[OMS + er*132 + i] * L[OEA + er*4];
          ushort_t hi, lo; split_t(d0v, hi, lo);
          LU[D0HI_US + er*200 + i] = hi;
          LU[D0LO_US + er*200 + i] = lo;
        }
      } else {
        int j = (a-8)*16 + c16;
        float b3 = rb3[320 + j];
        #pragma unroll
        for (int r=0;r<4;r++){
          int er = kg*4 + r;
          float dot = L[OMV+er*204      +j]*L[OEA+er*4+1]
                    + L[OMV+er*204+ 68  +j]*L[OEA+er*4+2]
                    + L[OMV+er*204+136  +j]*L[OEA+er*4+3];
          float d0v = (acc[r]+b3) * dot * 0.5773502691896258f;
          ushort_t hi, lo; split_t(d0v, hi, lo);
          LU[D0HI_US + er*200 + 128 + j] = hi;
          LU[D0LO_US + er*200 + 128 + j] = lo;
        }
      }
    }
    #pragma unroll
    for (int pi=0; pi<4; pi++){
      int p = w*4 + pi;
      f32x4 acc = {0.f,0.f,0.f,0.f};
      __builtin_amdgcn_s_setprio(1);
      acc = MFMA(ah0,pp0[pi],acc); acc = MFMA(ah1,pp1[pi],acc);
      __builtin_amdgcn_s_setprio(0);
      int q = p*16 + c16;
      if (q < 128){
        float b3 = rb3[128 + q];
        #pragma unroll
        for (int r=0;r<4;r++){
          int er = kg*4 + r;
          LU[ASV_US + er*136 + q] = tbf((acc[r]+b3) * L[OMS + er*132 + q]);
        }
      } else if (q < 192){
        float b3 = rb3[256 + (q-128)];
        #pragma unroll
        for (int r=0;r<4;r++){
          int er = kg*4 + r;
          L[OBVS + er*68 + (q-128)] = (acc[r]+b3) * L[OEA + er*4];
        }
      } else {
        float b3 = rb3[384 + (q-192)];
        #pragma unroll
        for (int r=0;r<4;r++){
          int er = kg*4 + r;
          L[OWV1 + er*68 + (q-192)] = (acc[r]+b3) * 0.7071067811865476f;
        }
      }
    }
  }
  __syncthreads();

  // ---- P4 ----
  const float rs192 = 0.07216878364870323f;
  if (w < 2){
    int nt = w;
    s16x8 bh[6], bl[6];
    #pragma unroll
    for (int kt=0;kt<6;kt++){
      bh[kt] = *(const s16x8*)&pk[PK_LW0AH + (size_t)((nt*6+kt)*64+lane)*8];
      bl[kt] = *(const s16x8*)&pk[PK_LW0AL + (size_t)((nt*6+kt)*64+lane)*8];
    }
    s16x8 ah[6], al[6];
    #pragma unroll
    for (int kt=0;kt<6;kt++){
      ah[kt] = *(const s16x8*)&LU[D0HI_US + arow*200 + kt*32 + kg*8];
      al[kt] = *(const s16x8*)&LU[D0LO_US + arow*200 + kt*32 + kg*8];
    }
    f32x4 acc = {0.f,0.f,0.f,0.f};
    __builtin_amdgcn_s_setprio(1);
    #pragma unroll
    for (int kt=0;kt<6;kt++){
      acc = MFMA(ah[kt],bh[kt],acc); acc = MFMA(ah[kt],bl[kt],acc); acc = MFMA(al[kt],bh[kt],acc);
    }
    __builtin_amdgcn_s_setprio(0);
    int q = nt*16 + c16;
    int realcol = (q>>3)*40 + (q&7);
    float lbv = lb0[realcol];
    float ad  = alpha_dot[q];
    #pragma unroll
    for (int r=0;r<4;r++){
      float m = acc[r]*rs192 + lbv;
      float p = m*(0.2f + 0.8f*sigmoidf_(m))*ad;
      p += __shfl_xor(p, 1);
      p += __shfl_xor(p, 2);
      p += __shfl_xor(p, 4);
      if ((lane&7)==0){
        int er = kg*4 + r;
        galpha[(size_t)(e0+er)*4 + (q>>3)] = p;
      }
    }
  } else {
    s16x8 af[6];
    #pragma unroll
    for (int kt=0;kt<6;kt++)
      af[kt] = *(const s16x8*)&LU[D0HI_US + arow*200 + kt*32 + kg*8];
    // software-pipelined j-loop: bA/bB double buffer (static indexing)
    int v0 = (w-2)*4;
    s16x8 bA[6], bB[6];
    #pragma unroll
    for (int kt=0;kt<6;kt++)
      bA[kt] = *(const s16x8*)&pk[PK_LW0P + (size_t)((v0*6+kt)*64+lane)*8];
    { // j = 0 (prefetch j=1 into bB)
      #pragma unroll
      for (int kt=0;kt<6;kt++)
        bB[kt] = *(const s16x8*)&pk[PK_LW0P + (size_t)(((v0+1)*6+kt)*64+lane)*8];
      f32x4 acc = {0.f,0.f,0.f,0.f};
      __builtin_amdgcn_s_setprio(1);
      #pragma unroll
      for (int kt=0;kt<6;kt++) acc = MFMA(af[kt],bA[kt],acc);
      __builtin_amdgcn_s_setprio(0);
      int q = v0*16 + c16;
      int realcol = (q>>5)*40 + 8 + (q&31);
      float lbv = lb0[realcol];
      #pragma unroll
      for (int r=0;r<4;r++){
        int er = kg*4 + r;
        gval[(size_t)(e0+er)*128 + q] = __float2bfloat16(acc[r]*rs192 + lbv);
      }
    }
    { // j = 1 (prefetch j=2 into bA)
      #pragma unroll
      for (int kt=0;kt<6;kt++)
        bA[kt] = *(const s16x8*)&pk[PK_LW0P + (size_t)(((v0+2)*6+kt)*64+lane)*8];
      f32x4 acc = {0.f,0.f,0.f,0.f};
      __builtin_amdgcn_s_setprio(1);
      #pragma unroll
      for (int kt=0;kt<6;kt++) acc = MFMA(af[kt],bB[kt],acc);
      __builtin_amdgcn_s_setprio(0);
      int q = (v0+1)*16 + c16;
      int realcol = (q>>5)*40 + 8 + (q&31);
      float lbv = lb0[realcol];
      #pragma unroll
      for (int r=0;r<4;r++){
        int er = kg*4 + r;
        gval[(size_t)(e0+er)*128 + q] = __float2bfloat16(acc[r]*rs192 + lbv);
      }
    }
    { // j = 2 (prefetch j=3 into bB)
      #pragma unroll
      for (int kt=0;kt<6;kt++)
        bB[kt] = *(const s16x8*)&pk[PK_LW0P + (size_t)(((v0+3)*6+kt)*64+lane)*8];
      f32x4 acc = {0.f,0.f,0.f,0.f};
      __builtin_amdgcn_s_setprio(1);
      #pragma unroll
      for (int kt=0;kt<6;kt++) acc = MFMA(af[kt],bA[kt],acc);
      __builtin_amdgcn_s_setprio(0);
      int q = (v0+2)*16 + c16;
      int realcol = (q>>5)*40 + 8 + (q&31);
      float lbv = lb0[realcol];
      #pragma unroll
      for (int r=0;r<4;r++){
        int er = kg*4 + r;
        gval[(size_t)(e0+er)*128 + q] = __float2bfloat16(acc[r]*rs192 + lbv);
      }
    }
    { // j = 3
      f32x4 acc = {0.f,0.f,0.f,0.f};
      __builtin_amdgcn_s_setprio(1);
      #pragma unroll
      for (int kt=0;kt<6;kt++) acc = MFMA(af[kt],bB[kt],acc);
      __builtin_amdgcn_s_setprio(0);
      int q = (v0+3)*16 + c16;
      int realcol = (q>>5)*40 + 8 + (q&31);
      float lbv = lb0[realcol];
      #pragma unroll
      for (int r=0;r<4;r++){
        int er = kg*4 + r;
        gval[(size_t)(e0+er)*128 + q] = __float2bfloat16(acc[r]*rs192 + lbv);
      }
    }
  }
  __syncthreads();

  // ---- P5-prep: prefetch P5 B-fragments first ----
  s16x8 p5b[8];
  #pragma unroll
  for (int kt=0;kt<8;kt++)
    p5b[kt] = *(const s16x8*)&pk[PK_LW1P + (size_t)((w*8+kt)*64+lane)*8];
  for (int idx=t; idx<1536; idx+=256){
    int c = idx>>9, rem = idx&511, e = rem>>5, i4 = rem&31;
    int i = i4*4;
    float4 r;
    if (i < 64){
      float4 b = *(const float4*)&L[OBVS + e*68 + i];
      float4 m = *(const float4*)&L[OMV + e*204 + c*68 + i];
      r.x=b.x*m.x; r.y=b.y*m.y; r.z=b.z*m.z; r.w=b.w*m.w;
    } else {
      int ii = i - 64;
      int ca = (c+1)%3, cb = (c+2)%3;
      float4 wv = *(const float4*)&L[OWV1 + e*68 + ii];
      float4 ma = *(const float4*)&L[OMV + e*204 + ca*68 + ii];
      float4 mb = *(const float4*)&L[OMV + e*204 + cb*68 + ii];
      float eaa = L[OEA + e*4 + 1 + ca], ebb = L[OEA + e*4 + 1 + cb];
      r.x = wv.x*(ma.x*ebb - mb.x*eaa);
      r.y = wv.y*(ma.y*ebb - mb.y*eaa);
      r.z = wv.z*(ma.z*ebb - mb.z*eaa);
      r.w = wv.w*(ma.w*ebb - mb.w*eaa);
    }
    uint2 u2v;
    u2v.x = pack2t(r.x, r.y);
    u2v.y = pack2t(r.z, r.w);
    *(uint2*)&LU[D1_US + c*2176 + e*136 + i] = u2v;
  }
  __syncthreads();

  // ---- P5 ----
  {
    f32x4 z = {0.f,0.f,0.f,0.f};
    __builtin_amdgcn_s_setprio(1);
    #pragma unroll
    for (int kt=0; kt<4; kt++){
      s16x8 a = *(const s16x8*)&LU[ASV_US + arow*136 + kt*32 + kg*8];
      z = MFMA(a,p5b[kt],z);
    }
    __builtin_amdgcn_s_setprio(0);
    f32x4 acc0 = {0.f,0.f,0.f,0.f}, acc1 = {0.f,0.f,0.f,0.f}, acc2 = {0.f,0.f,0.f,0.f};
    __builtin_amdgcn_s_setprio(1);
    #pragma unroll
    for (int kt=4; kt<8; kt++){
      s16x8 af0 = *(const s16x8*)&LU[D1_US + 0*2176 + arow*136 + (kt-4)*32 + kg*8];
      s16x8 af1 = *(const s16x8*)&LU[D1_US + 1*2176 + arow*136 + (kt-4)*32 + kg*8];
      s16x8 af2 = *(const s16x8*)&LU[D1_US + 2*2176 + arow*136 + (kt-4)*32 + kg*8];
      acc0 = MFMA(af0,p5b[kt],acc0); acc1 = MFMA(af1,p5b[kt],acc1); acc2 = MFMA(af2,p5b[kt],acc2);
    }
    __builtin_amdgcn_s_setprio(0);
    const float r16 = 0.0625f;
    int col = w*16 + c16;
    #pragma unroll
    for (int r=0;r<4;r++){
      int er = kg*4 + r;
      float ev0 = L[OEA + er*4 + 1];
      float ev1 = L[OEA + er*4 + 2];
      float ev2 = L[OEA + er*4 + 3];
      gm1[((size_t)(e0+er)*3 + 0)*64 + col] = __float2bfloat16((z[r]*ev0 + acc0[r])*r16);
      gm1[((size_t)(e0+er)*3 + 1)*64 + col] = __float2bfloat16((z[r]*ev1 + acc1[r])*r16);
      gm1[((size_t)(e0+er)*3 + 2)*64 + col] = __float2bfloat16((z[r]*ev2 + acc2[r])*r16);
    }
  }
}

// ---------------- Kernel D v2: pw0 fragment hoist + setprio ----------------
__global__ __launch_bounds__(256) void k_agg2(
  const int* __restrict__ edge_dst,
  const float* __restrict__ galpha, const __hip_bfloat16* __restrict__ gval,
  const __hip_bfloat16* __restrict__ gm1,
  const float* __restrict__ pb0, const ushort_t* __restrict__ pk,
  float* __restrict__ out)
{
  __shared__ __align__(16) float sNS[16*132];
  __shared__ __align__(16) float sNV[3*16*68];
  __shared__ float sAm[64], sInv[64];
  __shared__ int sB[17];
  const int t = threadIdx.x;
  const int n0 = blockIdx.x*16;
  const int lane = t&63, w = t>>6, arow = lane&15, kg = lane>>4, c16 = lane&15;

  if (t < 17){
    int target = n0 + t;
    int a=0,b=N_EDGES;
    while(a<b){ int m=(a+b)>>1; if (edge_dst[m] < target) a=m+1; else b=m; }
    sB[t]=a;
  }
  __syncthreads();
  // hoisted pw0 fragments for first output tile (nt = w*2), covered by softmax+accum
  s16x8 pwh[4], pwl[4];
  {
    int nt = w*2;
    #pragma unroll
    for (int kt=0;kt<4;kt++){
      pwh[kt] = *(const s16x8*)&pk[PK_PW0H + (size_t)((nt*4+kt)*64+lane)*8];
      pwl[kt] = *(const s16x8*)&pk[PK_PW0L + (size_t)((nt*4+kt)*64+lane)*8];
    }
  }
  {
    int p = t>>2, g = t&3;
    int node = p>>2, h = p&3;
    int lo = sB[node], hi = sB[node+1];
    float m = -1e30f;
    for (int e=lo+g; e<hi; e+=4) m = fmaxf(m, galpha[(size_t)e*4+h]);
    m = fmaxf(m, __shfl_xor(m,1));
    m = fmaxf(m, __shfl_xor(m,2));
    float am = (hi>lo) ? m : 0.f;
    float s = 0.f;
    for (int e=lo+g; e<hi; e+=4) s += __expf(galpha[(size_t)e*4+h]-am);
    s += __shfl_xor(s,1);
    s += __shfl_xor(s,2);
    if (g==0){ sAm[p]=am; sInv[p]=1.f/fmaxf(s,1e-12f); }
  }
  __syncthreads();
  {
    int node = t>>4, t2 = t&15, h = t2>>2, j = t2&3;
    int lo = sB[node], hi = sB[node+1];
    float am = sAm[node*4+h], inv = sInv[node*4+h];
    float av[8];  float am1[12];
    #pragma unroll
    for (int i=0;i<8;i++) av[i]=0.f;
    #pragma unroll
    for (int i=0;i<12;i++) am1[i]=0.f;
    for (int e=lo; e<hi; e++){
      float wgt = __expf(galpha[(size_t)e*4+h]-am)*inv;
      ushort4 v0 = *(const ushort4*)&gval[(size_t)e*128 + h*32 + j*8];
      ushort4 v1 = *(const ushort4*)&gval[(size_t)e*128 + h*32 + j*8 + 4];
      av[0] += wgt*bf2f(v0.x); av[1] += wgt*bf2f(v0.y);
      av[2] += wgt*bf2f(v0.z); av[3] += wgt*bf2f(v0.w);
      av[4] += wgt*bf2f(v1.x); av[5] += wgt*bf2f(v1.y);
      av[6] += wgt*bf2f(v1.z); av[7] += wgt*bf2f(v1.w);
      #pragma unroll
      for (int c=0;c<3;c++){
        ushort4 mv = *(const ushort4*)&gm1[((size_t)e*3+c)*64 + h*16 + j*4];
        am1[c*4+0] += wgt*bf2f(mv.x); am1[c*4+1] += wgt*bf2f(mv.y);
        am1[c*4+2] += wgt*bf2f(mv.z); am1[c*4+3] += wgt*bf2f(mv.w);
      }
    }
    #pragma unroll
    for (int i=0;i<8;i++) sNS[node*132 + h*32 + j*8 + i] = av[i];
    #pragma unroll
    for (int c=0;c<3;c++)
      #pragma unroll
      for (int i=0;i<4;i++) sNV[c*1088 + node*68 + h*16 + j*4 + i] = am1[c*4+i];
  }
  __syncthreads();
  const float rs128 = 0.08838834764831845f;
  {
    s16x8 ah[4], al[4];
    #pragma unroll
    for (int kt=0;kt<4;kt++)
      build_split8(&sNS[arow*132 + kt*32 + kg*8], ah[kt], al[kt]);
    { // q2 = 0: uses hoisted pwh/pwl
      f32x4 acc = {0.f,0.f,0.f,0.f};
      __builtin_amdgcn_s_setprio(1);
      #pragma unroll
      for (int kt=0;kt<4;kt++){
        acc = MFMA(ah[kt],pwh[kt],acc); acc = MFMA(ah[kt],pwl[kt],acc); acc = MFMA(al[kt],pwh[kt],acc);
      }
      __builtin_amdgcn_s_setprio(0);
      int nt = w*2;
      int col = nt*16 + c16;
      float bb = pb0[col];
      #pragma unroll
      for (int r=0;r<4;r++)
        out[(size_t)(n0 + kg*4 + r)*320 + col] = acc[r]*rs128 + bb;
    }
    { // q2 = 1
      int nt = w*2 + 1;
      f32x4 acc = {0.f,0.f,0.f,0.f};
      #pragma unroll
      for (int kt=0;kt<4;kt++){
        s16x8 bh = *(const s16x8*)&pk[PK_PW0H + (size_t)((nt*4+kt)*64+lane)*8];
        s16x8 bl = *(const s16x8*)&pk[PK_PW0L + (size_t)((nt*4+kt)*64+lane)*8];
        acc = MFMA(ah[kt],bh,acc); acc = MFMA(ah[kt],bl,acc); acc = MFMA(al[kt],bh,acc);
      }
      int col = nt*16 + c16;
      float bb = pb0[col];
      #pragma unroll
      for (int r=0;r<4;r++)
        out[(size_t)(n0 + kg*4 + r)*320 + col] = acc[r]*rs128 + bb;
    }
  }
  #pragma unroll
  for (int q2=0; q2<3; q2++){
    int p3 = w*3 + q2;
    int c = p3>>2, nt = p3&3;
    s16x8 ah[2], al[2];
    #pragma unroll
    for (int kt=0;kt<2;kt++)
      build_split8(&sNV[c*1088 + arow*68 + kt*32 + kg*8], ah[kt], al[kt]);
    f32x4 acc = {0.f,0.f,0.f,0.f};
    #pragma unroll
    for (int kt=0;kt<2;kt++){
      s16x8 bh = *(const s16x8*)&pk[PK_PW1H + (size_t)((nt*2+kt)*64+lane)*8];
      s16x8 bl = *(const s16x8*)&pk[PK_PW1L + (size_t)((nt*2+kt)*64+lane)*8];
      acc = MFMA(ah[kt],bh,acc); acc = MFMA(ah[kt],bl,acc); acc = MFMA(al[kt],bh,acc);
    }
    int col = nt*16 + c16;
    #pragma unroll
    for (int r=0;r<4;r++)
      out[(size_t)(n0 + kg*4 + r)*320 + 128 + col*3 + c] = acc[r]*0.125f;
  }
}

extern "C" void kernel_launch(void* const* d_in, const int* in_sizes, int n_in,
                              void* d_out, int out_size, void* d_ws, size_t ws_size,
                              hipStream_t stream)
{
  const float* node_input  = (const float*)d_in[0];
  const float* edge_attr   = (const float*)d_in[1];
  const float* edge_scalars= (const float*)d_in[2];
  const int*   edge_src    = (const int*)d_in[3];
  const int*   edge_dst    = (const int*)d_in[4];
  const float* w_src0=(const float*)d_in[5];  const float* b_src0=(const float*)d_in[6];
  const float* w_src1=(const float*)d_in[7];
  const float* w_dst0=(const float*)d_in[8];  const float* b_dst0=(const float*)d_in[9];
  const float* w_dst1=(const float*)d_in[10];
  const float* rw1=(const float*)d_in[11];    const float* rb1=(const float*)d_in[12];
  const float* rw2=(const float*)d_in[13];    const float* rb2=(const float*)d_in[14];
  const float* rw3=(const float*)d_in[15];    const float* rb3=(const float*)d_in[16];
  const float* lw0=(const float*)d_in[17];    const float* lb0=(const float*)d_in[18];
  const float* lw1=(const float*)d_in[19];
  const float* alpha_dot=(const float*)d_in[20];
  const float* pw0=(const float*)d_in[21];    const float* pb0=(const float*)d_in[22];
  const float* pw1=(const float*)d_in[23];
  float* out = (float*)d_out;

  float* ns_src = (float*)d_ws;
  float* ns_dst = ns_src + (size_t)N_NODES*128;
  float* nv_src = ns_dst + (size_t)N_NODES*128;
  float* nv_dst = nv_src + (size_t)N_NODES*192;
  float* galpha = nv_dst + (size_t)N_NODES*192;
  __hip_bfloat16* gval = (__hip_bfloat16*)(galpha + (size_t)N_EDGES*4);
  __hip_bfloat16* gm1  = gval + (size_t)N_EDGES*128;
  ushort_t* pk = (ushort_t*)(gm1 + (size_t)N_EDGES*192);

  k_pack<<<568, 256, 0, stream>>>(rw1, rw2, rw3, lw0, lw1, pw0, pw1,
                                  w_src0, w_dst0, w_src1, w_dst1, pk);
  k_node2<<<N_NODES/16, 256, 0, stream>>>(node_input, b_src0, b_dst0, pk,
                                          ns_src, ns_dst, nv_src, nv_dst);
  k_edge10<<<N_EDGES/EB, 256, 0, stream>>>(edge_attr, edge_scalars, edge_src, edge_dst,
                                           ns_src,ns_dst,nv_src,nv_dst,
                                           rb1,rb2,rb3,lb0,alpha_dot,pk,
                                           galpha,gval,gm1);
  k_agg2<<<N_NODES/16, 256, 0, stream>>>(edge_dst, galpha, gval, gm1, pb0, pk, out);
}

// Round 16
// 195.478 us; speedup vs baseline: 1.0337x; 1.0337x over previous
//
#include <hip/hip_runtime.h>
#include <hip/hip_bf16.h>
#include <math.h>

#define N_NODES 10000
#define N_EDGES 160000
#define EB 16

typedef unsigned short ushort_t;
using f32x4 = __attribute__((ext_vector_type(4))) float;
using s16x8 = __attribute__((ext_vector_type(8))) short;

__device__ __forceinline__ float sigmoidf_(float x){ return 1.f/(1.f+__expf(-x)); }
__device__ __forceinline__ ushort_t f2bf(float x){
  __hip_bfloat16 h = __float2bfloat16(x);
  return *reinterpret_cast<ushort_t*>(&h);
}
__device__ __forceinline__ float bf2f(ushort_t u){
  unsigned int v = ((unsigned int)u)<<16;
  return __uint_as_float(v);
}
__device__ __forceinline__ ushort_t tbf(float x){
  return (ushort_t)(__float_as_uint(x) >> 16);
}
__device__ __forceinline__ void split_t(float x, ushort_t &hi, ushort_t &lo){
  unsigned xb = __float_as_uint(x);
  hi = (ushort_t)(xb >> 16);
  float l = x - __uint_as_float(xb & 0xFFFF0000u);
  lo = (ushort_t)(__float_as_uint(l) >> 16);
}
#define PSEL 0x07060302u
__device__ __forceinline__ unsigned pack2t(float x0, float x1){
  return __builtin_amdgcn_perm(__float_as_uint(x1), __float_as_uint(x0), PSEL);
}
union SplitU { uint4 u; s16x8 v; };
__device__ __forceinline__ void build_split8(const float* __restrict__ src, s16x8 &ah, s16x8 &al){
  float4 xa = *(const float4*)&src[0];
  float4 xb = *(const float4*)&src[4];
  float x[8] = {xa.x,xa.y,xa.z,xa.w,xb.x,xb.y,xb.z,xb.w};
  SplitU H, L;
  #pragma unroll
  for (int p=0;p<4;p++){
    unsigned b0 = __float_as_uint(x[2*p]), b1 = __float_as_uint(x[2*p+1]);
    ((unsigned*)&H.u)[p] = __builtin_amdgcn_perm(b1, b0, PSEL);
    float l0 = x[2*p]   - __uint_as_float(b0 & 0xFFFF0000u);
    float l1 = x[2*p+1] - __uint_as_float(b1 & 0xFFFF0000u);
    ((unsigned*)&L.u)[p] = __builtin_amdgcn_perm(__float_as_uint(l1), __float_as_uint(l0), PSEL);
  }
  ah = H.v; al = L.v;
}

// ---- packed-weight ushort offsets (in pk) ----
#define PK_RW1H  0
#define PK_RW1L  4096
#define PK_RW2H  8192
#define PK_RW2L  12288
#define PK_RW3AH 16384
#define PK_RW3AL 28672
#define PK_RW3P  40960
#define PK_LW0AH 57344
#define PK_LW0AL 63488
#define PK_LW0P  69632
#define PK_LW1P  94208
#define PK_PW0H  110592
#define PK_PW0L  126976
#define PK_PW1H  143360
#define PK_PW1L  147456
#define PK_NS0H  151552
#define PK_NS0L  167936
#define PK_ND0H  184320
#define PK_ND0L  200704
#define PK_NS1H  217088
#define PK_NS1L  221184
#define PK_ND1H  225280
#define PK_ND1L  229376
#define PK_TOTAL 233472

// ---------------- k_pack ----------------
__global__ __launch_bounds__(256) void k_pack(
  const float* __restrict__ rw1, const float* __restrict__ rw2,
  const float* __restrict__ rw3, const float* __restrict__ lw0,
  const float* __restrict__ lw1, const float* __restrict__ pw0,
  const float* __restrict__ pw1,
  const float* __restrict__ w_src0, const float* __restrict__ w_dst0,
  const float* __restrict__ w_src1, const float* __restrict__ w_dst1,
  ushort_t* __restrict__ pk)
{
  int idx = blockIdx.x*256 + threadIdx.x;
  if (idx < 4096){
    int nt=idx>>10, r=idx&1023, kt=r>>9, q=r&511, l=q>>3, i=q&7;
    int k = kt*32 + (l>>4)*8 + i, col = nt*16 + (l&15);
    float x = rw1[k*64 + col];
    ushort_t hi = f2bf(x);
    pk[PK_RW1H+idx] = hi; pk[PK_RW1L+idx] = f2bf(x - bf2f(hi));
  } else if (idx < 8192){
    int j = idx-4096;
    int nt=j>>10, r=j&1023, kt=r>>9, q=r&511, l=q>>3, i=q&7;
    int k = kt*32 + (l>>4)*8 + i, col = nt*16 + (l&15);
    float x = rw2[k*64 + col];
    ushort_t hi = f2bf(x);
    pk[PK_RW2H+j] = hi; pk[PK_RW2L+j] = f2bf(x - bf2f(hi));
  } else if (idx < 20480){
    int j = idx-8192;
    int nt=j>>10, r=j&1023, kt=r>>9, q=r&511, l=q>>3, i=q&7;
    int k = kt*32 + (l>>4)*8 + i;
    int col = (nt<8) ? nt*16+(l&15) : 320+(nt-8)*16+(l&15);
    float x = rw3[(size_t)k*448 + col];
    ushort_t hi = f2bf(x);
    pk[PK_RW3AH+j] = hi; pk[PK_RW3AL+j] = f2bf(x - bf2f(hi));
  } else if (idx < 36864){
    int j = idx-20480;
    int nt=j>>10, r=j&1023, kt=r>>9, q=r&511, l=q>>3, i=q&7;
    int k = kt*32 + (l>>4)*8 + i;
    int v = nt*16 + (l&15);
    int col = (v<128) ? 128+v : (v<192) ? 256+(v-128) : 384+(v-192);
    pk[PK_RW3P+j] = f2bf(rw3[(size_t)k*448 + col]);
  } else if (idx < 43008){
    int j = idx-36864;
    int nt=j/3072, r=j-nt*3072, kt=r>>9, q=r&511, l=q>>3, i=q&7;
    int k = kt*32 + (l>>4)*8 + i;
    int qq = nt*16 + (l&15);
    int col = (qq>>3)*40 + (qq&7);
    float x = lw0[(size_t)k*160 + col];
    ushort_t hi = f2bf(x);
    pk[PK_LW0AH+j] = hi; pk[PK_LW0AL+j] = f2bf(x - bf2f(hi));
  } else if (idx < 67584){
    int j = idx-43008;
    int nt=j/3072, r=j-nt*3072, kt=r>>9, q=r&511, l=q>>3, i=q&7;
    int k = kt*32 + (l>>4)*8 + i;
    int v = nt*16 + (l&15);
    int col = (v>>5)*40 + 8 + (v&31);
    pk[PK_LW0P+j] = f2bf(lw0[(size_t)k*160 + col]);
  } else if (idx < 83968){
    int j = idx-67584;
    int nt=j>>12, r=j&4095, kt=r>>9, q=r&511, l=q>>3, i=q&7;
    int k = kt*32 + (l>>4)*8 + i, col = nt*16 + (l&15);
    pk[PK_LW1P+j] = f2bf(lw1[(size_t)k*64 + col]);
  } else if (idx < 100352){
    int j = idx-83968;
    int nt=j>>11, r=j&2047, kt=r>>9, q=r&511, l=q>>3, i=q&7;
    int k = kt*32 + (l>>4)*8 + i, col = nt*16 + (l&15);
    float x = pw0[k*128 + col];
    ushort_t hi = f2bf(x);
    pk[PK_PW0H+j] = hi; pk[PK_PW0L+j] = f2bf(x - bf2f(hi));
  } else if (idx < 104448){
    int j = idx-100352;
    int nt=j>>10, r=j&1023, kt=r>>9, q=r&511, l=q>>3, i=q&7;
    int k = kt*32 + (l>>4)*8 + i, col = nt*16 + (l&15);
    float x = pw1[k*64 + col];
    ushort_t hi = f2bf(x);
    pk[PK_PW1H+j] = hi; pk[PK_PW1L+j] = f2bf(x - bf2f(hi));
  } else if (idx < 120832){
    int j = idx-104448;
    int nt=j>>11, r=j&2047, kt=r>>9, q=r&511, l=q>>3, i=q&7;
    int k = kt*32 + (l>>4)*8 + i, col = nt*16 + (l&15);
    float x = w_src0[k*128 + col];
    ushort_t hi = f2bf(x);
    pk[PK_NS0H+j] = hi; pk[PK_NS0L+j] = f2bf(x - bf2f(hi));
  } else if (idx < 137216){
    int j = idx-120832;
    int nt=j>>11, r=j&2047, kt=r>>9, q=r&511, l=q>>3, i=q&7;
    int k = kt*32 + (l>>4)*8 + i, col = nt*16 + (l&15);
    float x = w_dst0[k*128 + col];
    ushort_t hi = f2bf(x);
    pk[PK_ND0H+j] = hi; pk[PK_ND0L+j] = f2bf(x - bf2f(hi));
  } else if (idx < 141312){
    int j = idx-137216;
    int nt=j>>10, r=j&1023, kt=r>>9, q=r&511, l=q>>3, i=q&7;
    int k = kt*32 + (l>>4)*8 + i, col = nt*16 + (l&15);
    float x = w_src1[k*64 + col];
    ushort_t hi = f2bf(x);
    pk[PK_NS1H+j] = hi; pk[PK_NS1L+j] = f2bf(x - bf2f(hi));
  } else if (idx < 145408){
    int j = idx-141312;
    int nt=j>>10, r=j&1023, kt=r>>9, q=r&511, l=q>>3, i=q&7;
    int k = kt*32 + (l>>4)*8 + i, col = nt*16 + (l&15);
    float x = w_dst1[k*64 + col];
    ushort_t hi = f2bf(x);
    pk[PK_ND1H+j] = hi; pk[PK_ND1L+j] = f2bf(x - bf2f(hi));
  }
}

#define MFMA(a,b,c) __builtin_amdgcn_mfma_f32_16x16x32_bf16((a),(b),(c),0,0,0)

// ---------------- k_node2 ----------------
__global__ __launch_bounds__(256) void k_node2(
  const float* __restrict__ node_input,
  const float* __restrict__ b_src0, const float* __restrict__ b_dst0,
  const ushort_t* __restrict__ pk,
  float* __restrict__ ns_src, float* __restrict__ ns_dst,
  float* __restrict__ nv_src, float* __restrict__ nv_dst)
{
  __shared__ __align__(16) float S[16*132 + 3*16*68];
  const int t = threadIdx.x, n0 = blockIdx.x*16;
  const int lane = t&63, w = t>>6, arow = lane&15, kg = lane>>4, c16 = lane&15;
  {
    int n = t>>4, l = t&15;
    const float* row = &node_input[(size_t)(n0+n)*320];
    *(float4*)&S[n*132 + l*8 + 0] = *(const float4*)&row[l*8];
    *(float4*)&S[n*132 + l*8 + 4] = *(const float4*)&row[l*8+4];
    float f[12];
    #pragma unroll
    for (int j=0;j<3;j++){
      float4 a = *(const float4*)&row[128 + l*12 + j*4];
      f[j*4+0]=a.x; f[j*4+1]=a.y; f[j*4+2]=a.z; f[j*4+3]=a.w;
    }
    #pragma unroll
    for (int c=0;c<3;c++){
      float4 r; r.x=f[c]; r.y=f[3+c]; r.z=f[6+c]; r.w=f[9+c];
      *(float4*)&S[2112 + c*1088 + n*68 + l*4] = r;
    }
  }
  __syncthreads();
  const float rs128 = 0.08838834764831845f;
  {
    s16x8 ah[4], al[4];
    #pragma unroll
    for (int kt=0;kt<4;kt++)
      build_split8(&S[arow*132 + kt*32 + kg*8], ah[kt], al[kt]);
    #pragma unroll
    for (int q2=0;q2<4;q2++){
      int task = w*4+q2;
      int m = task>>3, nt = task&7;
      f32x4 acc = {0.f,0.f,0.f,0.f};
      #pragma unroll
      for (int kt=0;kt<4;kt++){
        s16x8 bh = *(const s16x8*)&pk[(m?PK_ND0H:PK_NS0H) + (size_t)((nt*4+kt)*64+lane)*8];
        s16x8 bl = *(const s16x8*)&pk[(m?PK_ND0L:PK_NS0L) + (size_t)((nt*4+kt)*64+lane)*8];
        acc = MFMA(ah[kt],bh,acc); acc = MFMA(ah[kt],bl,acc); acc = MFMA(al[kt],bh,acc);
      }
      int col = nt*16 + c16;
      float bv = (m ? b_dst0 : b_src0)[col];
      float* outp = m ? ns_dst : ns_src;
      #pragma unroll
      for (int r=0;r<4;r++)
        outp[(size_t)(n0 + kg*4 + r)*128 + col] = acc[r]*rs128 + bv;
    }
  }
  #pragma unroll
  for (int c=0;c<3;c++){
    s16x8 vah[2], vav[2];
    #pragma unroll
    for (int kt=0;kt<2;kt++)
      build_split8(&S[2112 + c*1088 + arow*68 + kt*32 + kg*8], vah[kt], vav[kt]);
    #pragma unroll
    for (int q2=0;q2<2;q2++){
      int task = w*2+q2;
      int m = task>>2, nt = task&3;
      f32x4 acc = {0.f,0.f,0.f,0.f};
      #pragma unroll
      for (int kt=0;kt<2;kt++){
        s16x8 bh = *(const s16x8*)&pk[(m?PK_ND1H:PK_NS1H) + (size_t)((nt*2+kt)*64+lane)*8];
        s16x8 bl = *(const s16x8*)&pk[(m?PK_ND1L:PK_NS1L) + (size_t)((nt*2+kt)*64+lane)*8];
        acc = MFMA(vah[kt],bh,acc); acc = MFMA(vah[kt],bl,acc); acc = MFMA(vav[kt],bh,acc);
      }
      int col = nt*16 + c16;
      float* outp = m ? nv_dst : nv_src;
      #pragma unroll
      for (int r=0;r<4;r++)
        outp[(size_t)(n0 + kg*4 + r)*192 + col*3 + c] = acc[r]*0.125f;
    }
  }
}

// ---------------- Kernel C: cross-barrier B-fragment prefetch (round-14 best) ----------------
#define OEA   0
#define OMV   64
#define OMS   3328
#define FX    5440
#define ESHI_US  (FX*2)
#define ESLO_US  (FX*2+1152)
#define D0HI_US  (FX*2)
#define D0LO_US  (FX*2+3200)
#define D1_US    (FX*2)
#define FY    8704
#define H1HI_US  (FY*2)
#define H1LO_US  (FY*2+1152)
#define ASV_US   (FY*2)
#define FH2   9856
#define H2HI_US  (FH2*2)
#define H2LO_US  (FH2*2+1152)
#define OBVS  11008
#define OWV1  12096

__global__ __launch_bounds__(256) void k_edge9(
  const float* __restrict__ edge_attr, const float* __restrict__ edge_scalars,
  const int* __restrict__ edge_src, const int* __restrict__ edge_dst,
  const float* __restrict__ ns_src, const float* __restrict__ ns_dst,
  const float* __restrict__ nv_src, const float* __restrict__ nv_dst,
  const float* __restrict__ rb1, const float* __restrict__ rb2,
  const float* __restrict__ rb3, const float* __restrict__ lb0,
  const float* __restrict__ alpha_dot,
  const ushort_t* __restrict__ pk,
  float* __restrict__ galpha, __hip_bfloat16* __restrict__ gval,
  __hip_bfloat16* __restrict__ gm1)
{
  __shared__ __align__(16) float L[13184];
  ushort_t* LU = (ushort_t*)L;
  const int t = threadIdx.x;
  const int e0 = blockIdx.x * EB;
  const int lane = t & 63, w = t >> 6;
  const int arow = lane & 15, kg = lane >> 4, c16 = lane & 15;

  // ---- PREFETCH P1 B-fragments (covered by P0 staging + barrier drain) ----
  s16x8 p1bh0 = *(const s16x8*)&pk[PK_RW1H + (size_t)((w*2+0)*64+lane)*8];
  s16x8 p1bl0 = *(const s16x8*)&pk[PK_RW1L + (size_t)((w*2+0)*64+lane)*8];
  s16x8 p1bh1 = *(const s16x8*)&pk[PK_RW1H + (size_t)((w*2+1)*64+lane)*8];
  s16x8 p1bl1 = *(const s16x8*)&pk[PK_RW1L + (size_t)((w*2+1)*64+lane)*8];

  // ---- P0 ----
  {
    int e = t>>4, l = t&15;
    int s = edge_src[e0+e], d = edge_dst[e0+e];
    #pragma unroll
    for (int j=0;j<2;j++){
      int idx = l + 16*j;
      float4 a = *(const float4*)&ns_src[(size_t)s*128 + idx*4];
      float4 b = *(const float4*)&ns_dst[(size_t)d*128 + idx*4];
      float4 r; r.x=a.x+b.x; r.y=a.y+b.y; r.z=a.z+b.z; r.w=a.w+b.w;
      *(float4*)&L[OMS + e*132 + idx*4] = r;
    }
    float f[12];
    #pragma unroll
    for (int j=0;j<3;j++){
      float4 a = *(const float4*)&nv_src[(size_t)s*192 + l*12 + j*4];
      float4 b = *(const float4*)&nv_dst[(size_t)d*192 + l*12 + j*4];
      f[j*4+0]=a.x+b.x; f[j*4+1]=a.y+b.y; f[j*4+2]=a.z+b.z; f[j*4+3]=a.w+b.w;
    }
    #pragma unroll
    for (int c=0;c<3;c++){
      float4 r; r.x=f[c]; r.y=f[3+c]; r.z=f[6+c]; r.w=f[9+c];
      *(float4*)&L[OMV + e*204 + c*68 + l*4] = r;
    }
    float4 x = *(const float4*)&edge_scalars[(size_t)(e0+e)*64 + l*4];
    unsigned b0=__float_as_uint(x.x), b1=__float_as_uint(x.y), b2=__float_as_uint(x.z), b3=__float_as_uint(x.w);
    uint2 hi2, lo2;
    hi2.x = __builtin_amdgcn_perm(b1, b0, PSEL);
    hi2.y = __builtin_amdgcn_perm(b3, b2, PSEL);
    float l0 = x.x - __uint_as_float(b0 & 0xFFFF0000u);
    float l1 = x.y - __uint_as_float(b1 & 0xFFFF0000u);
    float l2 = x.z - __uint_as_float(b2 & 0xFFFF0000u);
    float l3 = x.w - __uint_as_float(b3 & 0xFFFF0000u);
    lo2.x = pack2t(l0, l1);
    lo2.y = pack2t(l2, l3);
    *(uint2*)&LU[ESHI_US + e*72 + l*4] = hi2;
    *(uint2*)&LU[ESLO_US + e*72 + l*4] = lo2;
  }
  if (t < 64) L[OEA + t] = edge_attr[(size_t)e0*4 + t];
  __syncthreads();

  // ---- P1 (uses prefetched p1*; prefetch P2) ----
  s16x8 p2bh0 = *(const s16x8*)&pk[PK_RW2H + (size_t)((w*2+0)*64+lane)*8];
  s16x8 p2bl0 = *(const s16x8*)&pk[PK_RW2L + (size_t)((w*2+0)*64+lane)*8];
  s16x8 p2bh1 = *(const s16x8*)&pk[PK_RW2H + (size_t)((w*2+1)*64+lane)*8];
  s16x8 p2bl1 = *(const s16x8*)&pk[PK_RW2L + (size_t)((w*2+1)*64+lane)*8];
  {
    s16x8 ah0 = *(const s16x8*)&LU[ESHI_US + arow*72 + 0  + kg*8];
    s16x8 ah1 = *(const s16x8*)&LU[ESHI_US + arow*72 + 32 + kg*8];
    s16x8 al0 = *(const s16x8*)&LU[ESLO_US + arow*72 + 0  + kg*8];
    s16x8 al1 = *(const s16x8*)&LU[ESLO_US + arow*72 + 32 + kg*8];
    f32x4 acc = {0.f,0.f,0.f,0.f};
    acc = MFMA(ah0,p1bh0,acc); acc = MFMA(ah0,p1bl0,acc); acc = MFMA(al0,p1bh0,acc);
    acc = MFMA(ah1,p1bh1,acc); acc = MFMA(ah1,p1bl1,acc); acc = MFMA(al1,p1bh1,acc);
    int col = w*16 + c16;
    float rb = rb1[col];
    #pragma unroll
    for (int r=0;r<4;r++){
      int er = kg*4 + r;
      float v = acc[r] + rb;
      float h = v*sigmoidf_(v);
      ushort_t hi, lo; split_t(h, hi, lo);
      LU[H1HI_US + er*72 + col] = hi;
      LU[H1LO_US + er*72 + col] = lo;
    }
  }
  __syncthreads();

  // ---- P2 (uses p2*; prefetch P3 alpha tiles: 12 frags) ----
  s16x8 p3h0[3], p3l0[3], p3h1[3], p3l1[3];
  #pragma unroll
  for (int ai=0; ai<3; ai++){
    int a = w*3 + ai;
    p3h0[ai] = *(const s16x8*)&pk[PK_RW3AH + (size_t)((a*2+0)*64+lane)*8];
    p3l0[ai] = *(const s16x8*)&pk[PK_RW3AL + (size_t)((a*2+0)*64+lane)*8];
    p3h1[ai] = *(const s16x8*)&pk[PK_RW3AH + (size_t)((a*2+1)*64+lane)*8];
    p3l1[ai] = *(const s16x8*)&pk[PK_RW3AL + (size_t)((a*2+1)*64+lane)*8];
  }
  {
    s16x8 ah0 = *(const s16x8*)&LU[H1HI_US + arow*72 + 0  + kg*8];
    s16x8 ah1 = *(const s16x8*)&LU[H1HI_US + arow*72 + 32 + kg*8];
    s16x8 al0 = *(const s16x8*)&LU[H1LO_US + arow*72 + 0  + kg*8];
    s16x8 al1 = *(const s16x8*)&LU[H1LO_US + arow*72 + 32 + kg*8];
    f32x4 acc = {0.f,0.f,0.f,0.f};
    acc = MFMA(ah0,p2bh0,acc); acc = MFMA(ah0,p2bl0,acc); acc = MFMA(al0,p2bh0,acc);
    acc = MFMA(ah1,p2bh1,acc); acc = MFMA(ah1,p2bl1,acc); acc = MFMA(al1,p2bh1,acc);
    int col = w*16 + c16;
    float rb = rb2[col];
    #pragma unroll
    for (int r=0;r<4;r++){
      int er = kg*4 + r;
      float v = acc[r] + rb;
      float h = v*sigmoidf_(v);
      ushort_t hi, lo; split_t(h, hi, lo);
      LU[H2HI_US + er*72 + col] = hi;
      LU[H2LO_US + er*72 + col] = lo;
    }
  }
  __syncthreads();

  // ---- P3: payload loads issued first (covered by alpha MFMA chain) ----
  {
    s16x8 pp0[4], pp1[4];
    #pragma unroll
    for (int pi=0; pi<4; pi++){
      int p = w*4 + pi;
      pp0[pi] = *(const s16x8*)&pk[PK_RW3P + (size_t)((p*2+0)*64+lane)*8];
      pp1[pi] = *(const s16x8*)&pk[PK_RW3P + (size_t)((p*2+1)*64+lane)*8];
    }
    s16x8 ah0 = *(const s16x8*)&LU[H2HI_US + arow*72 + 0  + kg*8];
    s16x8 ah1 = *(const s16x8*)&LU[H2HI_US + arow*72 + 32 + kg*8];
    s16x8 al0 = *(const s16x8*)&LU[H2LO_US + arow*72 + 0  + kg*8];
    s16x8 al1 = *(const s16x8*)&LU[H2LO_US + arow*72 + 32 + kg*8];

    #pragma unroll
    for (int ai=0; ai<3; ai++){
      int a = w*3 + ai;
      f32x4 acc = {0.f,0.f,0.f,0.f};
      acc = MFMA(ah0,p3h0[ai],acc); acc = MFMA(ah0,p3l0[ai],acc); acc = MFMA(al0,p3h0[ai],acc);
      acc = MFMA(ah1,p3h1[ai],acc); acc = MFMA(ah1,p3l1[ai],acc); acc = MFMA(al1,p3h1[ai],acc);
      if (a < 8){
        int i = a*16 + c16;
        float b3 = rb3[i];
        #pragma unroll
        for (int r=0;r<4;r++){
          int er = kg*4 + r;
          float d0v = (acc[r]+b3) * L[OMS + er*132 + i] * L[OEA + er*4];
          ushort_t hi, lo; split_t(d0v, hi, lo);
          LU[D0HI_US + er*200 + i] = hi;
          LU[D0LO_US + er*200 + i] = lo;
        }
      } else {
        int j = (a-8)*16 + c16;
        float b3 = rb3[320 + j];
        #pragma unroll
        for (int r=0;r<4;r++){
          int er = kg*4 + r;
          float dot = L[OMV+er*204      +j]*L[OEA+er*4+1]
                    + L[OMV+er*204+ 68  +j]*L[OEA+er*4+2]
                    + L[OMV+er*204+136  +j]*L[OEA+er*4+3];
          float d0v = (acc[r]+b3) * dot * 0.5773502691896258f;
          ushort_t hi, lo; split_t(d0v, hi, lo);
          LU[D0HI_US + er*200 + 128 + j] = hi;
          LU[D0LO_US + er*200 + 128 + j] = lo;
        }
      }
    }
    #pragma unroll
    for (int pi=0; pi<4; pi++){
      int p = w*4 + pi;
      f32x4 acc = {0.f,0.f,0.f,0.f};
      acc = MFMA(ah0,pp0[pi],acc); acc = MFMA(ah1,pp1[pi],acc);
      int q = p*16 + c16;
      if (q < 128){
        float b3 = rb3[128 + q];
        #pragma unroll
        for (int r=0;r<4;r++){
          int er = kg*4 + r;
          LU[ASV_US + er*136 + q] = tbf((acc[r]+b3) * L[OMS + er*132 + q]);
        }
      } else if (q < 192){
        float b3 = rb3[256 + (q-128)];
        #pragma unroll
        for (int r=0;r<4;r++){
          int er = kg*4 + r;
          L[OBVS + er*68 + (q-128)] = (acc[r]+b3) * L[OEA + er*4];
        }
      } else {
        float b3 = rb3[384 + (q-192)];
        #pragma unroll
        for (int r=0;r<4;r++){
          int er = kg*4 + r;
          L[OWV1 + er*68 + (q-192)] = (acc[r]+b3) * 0.7071067811865476f;
        }
      }
    }
  }
  __syncthreads();

  // ---- P4 (B loads issued at phase top, arrays hoisted) ----
  const float rs192 = 0.07216878364870323f;
  if (w < 2){
    int nt = w;
    s16x8 bh[6], bl[6];
    #pragma unroll
    for (int kt=0;kt<6;kt++){
      bh[kt] = *(const s16x8*)&pk[PK_LW0AH + (size_t)((nt*6+kt)*64+lane)*8];
      bl[kt] = *(const s16x8*)&pk[PK_LW0AL + (size_t)((nt*6+kt)*64+lane)*8];
    }
    s16x8 ah[6], al[6];
    #pragma unroll
    for (int kt=0;kt<6;kt++){
      ah[kt] = *(const s16x8*)&LU[D0HI_US + arow*200 + kt*32 + kg*8];
      al[kt] = *(const s16x8*)&LU[D0LO_US + arow*200 + kt*32 + kg*8];
    }
    f32x4 acc = {0.f,0.f,0.f,0.f};
    #pragma unroll
    for (int kt=0;kt<6;kt++){
      acc = MFMA(ah[kt],bh[kt],acc); acc = MFMA(ah[kt],bl[kt],acc); acc = MFMA(al[kt],bh[kt],acc);
    }
    int q = nt*16 + c16;
    int realcol = (q>>3)*40 + (q&7);
    float lbv = lb0[realcol];
    float ad  = alpha_dot[q];
    #pragma unroll
    for (int r=0;r<4;r++){
      float m = acc[r]*rs192 + lbv;
      float p = (0.6f*m + 0.4f*m*(2.f*sigmoidf_(m)-1.f))*ad;
      p += __shfl_xor(p, 1);
      p += __shfl_xor(p, 2);
      p += __shfl_xor(p, 4);
      if ((lane&7)==0){
        int er = kg*4 + r;
        galpha[(size_t)(e0+er)*4 + (q>>3)] = p;
      }
    }
  } else {
    s16x8 af[6];
    #pragma unroll
    for (int kt=0;kt<6;kt++)
      af[kt] = *(const s16x8*)&LU[D0HI_US + arow*200 + kt*32 + kg*8];
    #pragma unroll
    for (int j=0;j<4;j++){
      int v = (w-2)*4 + j;
      f32x4 acc = {0.f,0.f,0.f,0.f};
      #pragma unroll
      for (int kt=0;kt<6;kt++){
        s16x8 b = *(const s16x8*)&pk[PK_LW0P + (size_t)((v*6+kt)*64+lane)*8];
        acc = MFMA(af[kt],b,acc);
      }
      int q = v*16 + c16;
      int realcol = (q>>5)*40 + 8 + (q&31);
      float lbv = lb0[realcol];
      #pragma unroll
      for (int r=0;r<4;r++){
        int er = kg*4 + r;
        gval[(size_t)(e0+er)*128 + q] = __float2bfloat16(acc[r]*rs192 + lbv);
      }
    }
  }
  __syncthreads();

  // ---- P5-prep: prefetch P5 B-fragments first (covered by LDS-only d1 build) ----
  s16x8 p5b[8];
  #pragma unroll
  for (int kt=0;kt<8;kt++)
    p5b[kt] = *(const s16x8*)&pk[PK_LW1P + (size_t)((w*8+kt)*64+lane)*8];
  for (int idx=t; idx<1536; idx+=256){
    int c = idx>>9, rem = idx&511, e = rem>>5, i4 = rem&31;
    int i = i4*4;
    float4 r;
    if (i < 64){
      float4 b = *(const float4*)&L[OBVS + e*68 + i];
      float4 m = *(const float4*)&L[OMV + e*204 + c*68 + i];
      r.x=b.x*m.x; r.y=b.y*m.y; r.z=b.z*m.z; r.w=b.w*m.w;
    } else {
      int ii = i - 64;
      int ca = (c+1)%3, cb = (c+2)%3;
      float4 wv = *(const float4*)&L[OWV1 + e*68 + ii];
      float4 ma = *(const float4*)&L[OMV + e*204 + ca*68 + ii];
      float4 mb = *(const float4*)&L[OMV + e*204 + cb*68 + ii];
      float eaa = L[OEA + e*4 + 1 + ca], ebb = L[OEA + e*4 + 1 + cb];
      r.x = wv.x*(ma.x*ebb - mb.x*eaa);
      r.y = wv.y*(ma.y*ebb - mb.y*eaa);
      r.z = wv.z*(ma.z*ebb - mb.z*eaa);
      r.w = wv.w*(ma.w*ebb - mb.w*eaa);
    }
    uint2 u2v;
    u2v.x = pack2t(r.x, r.y);
    u2v.y = pack2t(r.z, r.w);
    *(uint2*)&LU[D1_US + c*2176 + e*136 + i] = u2v;
  }
  __syncthreads();

  // ---- P5 (uses prefetched p5b) ----
  {
    f32x4 z = {0.f,0.f,0.f,0.f};
    #pragma unroll
    for (int kt=0; kt<4; kt++){
      s16x8 a = *(const s16x8*)&LU[ASV_US + arow*136 + kt*32 + kg*8];
      z = MFMA(a,p5b[kt],z);
    }
    f32x4 acc0 = {0.f,0.f,0.f,0.f}, acc1 = {0.f,0.f,0.f,0.f}, acc2 = {0.f,0.f,0.f,0.f};
    #pragma unroll
    for (int kt=4; kt<8; kt++){
      s16x8 af0 = *(const s16x8*)&LU[D1_US + 0*2176 + arow*136 + (kt-4)*32 + kg*8];
      s16x8 af1 = *(const s16x8*)&LU[D1_US + 1*2176 + arow*136 + (kt-4)*32 + kg*8];
      s16x8 af2 = *(const s16x8*)&LU[D1_US + 2*2176 + arow*136 + (kt-4)*32 + kg*8];
      acc0 = MFMA(af0,p5b[kt],acc0); acc1 = MFMA(af1,p5b[kt],acc1); acc2 = MFMA(af2,p5b[kt],acc2);
    }
    const float r16 = 0.0625f;
    int col = w*16 + c16;
    #pragma unroll
    for (int r=0;r<4;r++){
      int er = kg*4 + r;
      float ev0 = L[OEA + er*4 + 1];
      float ev1 = L[OEA + er*4 + 2];
      float ev2 = L[OEA + er*4 + 3];
      gm1[((size_t)(e0+er)*3 + 0)*64 + col] = __float2bfloat16((z[r]*ev0 + acc0[r])*r16);
      gm1[((size_t)(e0+er)*3 + 1)*64 + col] = __float2bfloat16((z[r]*ev1 + acc1[r])*r16);
      gm1[((size_t)(e0+er)*3 + 2)*64 + col] = __float2bfloat16((z[r]*ev2 + acc2[r])*r16);
    }
  }
}

// ---------------- Kernel D v2 ----------------
__global__ __launch_bounds__(256) void k_agg2(
  const int* __restrict__ edge_dst,
  const float* __restrict__ galpha, const __hip_bfloat16* __restrict__ gval,
  const __hip_bfloat16* __restrict__ gm1,
  const float* __restrict__ pb0, const ushort_t* __restrict__ pk,
  float* __restrict__ out)
{
  __shared__ __align__(16) float sNS[16*132];
  __shared__ __align__(16) float sNV[3*16*68];
  __shared__ float sAm[64], sInv[64];
  __shared__ int sB[17];
  const int t = threadIdx.x;
  const int n0 = blockIdx.x*16;
  const int lane = t&63, w = t>>6, arow = lane&15, kg = lane>>4, c16 = lane&15;

  if (t < 17){
    int target = n0 + t;
    int a=0,b=N_EDGES;
    while(a<b){ int m=(a+b)>>1; if (edge_dst[m] < target) a=m+1; else b=m; }
    sB[t]=a;
  }
  __syncthreads();
  {
    int p = t>>2, g = t&3;
    int node = p>>2, h = p&3;
    int lo = sB[node], hi = sB[node+1];
    float m = -1e30f;
    for (int e=lo+g; e<hi; e+=4) m = fmaxf(m, galpha[(size_t)e*4+h]);
    m = fmaxf(m, __shfl_xor(m,1));
    m = fmaxf(m, __shfl_xor(m,2));
    float am = (hi>lo) ? m : 0.f;
    float s = 0.f;
    for (int e=lo+g; e<hi; e+=4) s += __expf(galpha[(size_t)e*4+h]-am);
    s += __shfl_xor(s,1);
    s += __shfl_xor(s,2);
    if (g==0){ sAm[p]=am; sInv[p]=1.f/fmaxf(s,1e-12f); }
  }
  __syncthreads();
  {
    int node = t>>4, t2 = t&15, h = t2>>2, j = t2&3;
    int lo = sB[node], hi = sB[node+1];
    float am = sAm[node*4+h], inv = sInv[node*4+h];
    float av[8];  float am1[12];
    #pragma unroll
    for (int i=0;i<8;i++) av[i]=0.f;
    #pragma unroll
    for (int i=0;i<12;i++) am1[i]=0.f;
    for (int e=lo; e<hi; e++){
      float wgt = __expf(galpha[(size_t)e*4+h]-am)*inv;
      ushort4 v0 = *(const ushort4*)&gval[(size_t)e*128 + h*32 + j*8];
      ushort4 v1 = *(const ushort4*)&gval[(size_t)e*128 + h*32 + j*8 + 4];
      av[0] += wgt*bf2f(v0.x); av[1] += wgt*bf2f(v0.y);
      av[2] += wgt*bf2f(v0.z); av[3] += wgt*bf2f(v0.w);
      av[4] += wgt*bf2f(v1.x); av[5] += wgt*bf2f(v1.y);
      av[6] += wgt*bf2f(v1.z); av[7] += wgt*bf2f(v1.w);
      #pragma unroll
      for (int c=0;c<3;c++){
        ushort4 mv = *(const ushort4*)&gm1[((size_t)e*3+c)*64 + h*16 + j*4];
        am1[c*4+0] += wgt*bf2f(mv.x); am1[c*4+1] += wgt*bf2f(mv.y);
        am1[c*4+2] += wgt*bf2f(mv.z); am1[c*4+3] += wgt*bf2f(mv.w);
      }
    }
    #pragma unroll
    for (int i=0;i<8;i++) sNS[node*132 + h*32 + j*8 + i] = av[i];
    #pragma unroll
    for (int c=0;c<3;c++)
      #pragma unroll
      for (int i=0;i<4;i++) sNV[c*1088 + node*68 + h*16 + j*4 + i] = am1[c*4+i];
  }
  __syncthreads();
  const float rs128 = 0.08838834764831845f;
  {
    s16x8 ah[4], al[4];
    #pragma unroll
    for (int kt=0;kt<4;kt++)
      build_split8(&sNS[arow*132 + kt*32 + kg*8], ah[kt], al[kt]);
    #pragma unroll
    for (int q2=0; q2<2; q2++){
      int nt = w*2 + q2;
      f32x4 acc = {0.f,0.f,0.f,0.f};
      #pragma unroll
      for (int kt=0;kt<4;kt++){
        s16x8 bh = *(const s16x8*)&pk[PK_PW0H + (size_t)((nt*4+kt)*64+lane)*8];
        s16x8 bl = *(const s16x8*)&pk[PK_PW0L + (size_t)((nt*4+kt)*64+lane)*8];
        acc = MFMA(ah[kt],bh,acc); acc = MFMA(ah[kt],bl,acc); acc = MFMA(al[kt],bh,acc);
      }
      int col = nt*16 + c16;
      float bb = pb0[col];
      #pragma unroll
      for (int r=0;r<4;r++)
        out[(size_t)(n0 + kg*4 + r)*320 + col] = acc[r]*rs128 + bb;
    }
  }
  #pragma unroll
  for (int q2=0; q2<3; q2++){
    int p3 = w*3 + q2;
    int c = p3>>2, nt = p3&3;
    s16x8 ah[2], al[2];
    #pragma unroll
    for (int kt=0;kt<2;kt++)
      build_split8(&sNV[c*1088 + arow*68 + kt*32 + kg*8], ah[kt], al[kt]);
    f32x4 acc = {0.f,0.f,0.f,0.f};
    #pragma unroll
    for (int kt=0;kt<2;kt++){
      s16x8 bh = *(const s16x8*)&pk[PK_PW1H + (size_t)((nt*2+kt)*64+lane)*8];
      s16x8 bl = *(const s16x8*)&pk[PK_PW1L + (size_t)((nt*2+kt)*64+lane)*8];
      acc = MFMA(ah[kt],bh,acc); acc = MFMA(ah[kt],bl,acc); acc = MFMA(al[kt],bh,acc);
    }
    int col = nt*16 + c16;
    #pragma unroll
    for (int r=0;r<4;r++)
      out[(size_t)(n0 + kg*4 + r)*320 + 128 + col*3 + c] = acc[r]*0.125f;
  }
}

extern "C" void kernel_launch(void* const* d_in, const int* in_sizes, int n_in,
                              void* d_out, int out_size, void* d_ws, size_t ws_size,
                              hipStream_t stream)
{
  const float* node_input  = (const float*)d_in[0];
  const float* edge_attr   = (const float*)d_in[1];
  const float* edge_scalars= (const float*)d_in[2];
  const int*   edge_src    = (const int*)d_in[3];
  const int*   edge_dst    = (const int*)d_in[4];
  const float* w_src0=(const float*)d_in[5];  const float* b_src0=(const float*)d_in[6];
  const float* w_src1=(const float*)d_in[7];
  const float* w_dst0=(const float*)d_in[8];  const float* b_dst0=(const float*)d_in[9];
  const float* w_dst1=(const float*)d_in[10];
  const float* rw1=(const float*)d_in[11];    const float* rb1=(const float*)d_in[12];
  const float* rw2=(const float*)d_in[13];    const float* rb2=(const float*)d_in[14];
  const float* rw3=(const float*)d_in[15];    const float* rb3=(const float*)d_in[16];
  const float* lw0=(const float*)d_in[17];    const float* lb0=(const float*)d_in[18];
  const float* lw1=(const float*)d_in[19];
  const float* alpha_dot=(const float*)d_in[20];
  const float* pw0=(const float*)d_in[21];    const float* pb0=(const float*)d_in[22];
  const float* pw1=(const float*)d_in[23];
  float* out = (float*)d_out;

  float* ns_src = (float*)d_ws;
  float* ns_dst = ns_src + (size_t)N_NODES*128;
  float* nv_src = ns_dst + (size_t)N_NODES*128;
  float* nv_dst = nv_src + (size_t)N_NODES*192;
  float* galpha = nv_dst + (size_t)N_NODES*192;
  __hip_bfloat16* gval = (__hip_bfloat16*)(galpha + (size_t)N_EDGES*4);
  __hip_bfloat16* gm1  = gval + (size_t)N_EDGES*128;
  ushort_t* pk = (ushort_t*)(gm1 + (size_t)N_EDGES*192);

  k_pack<<<568, 256, 0, stream>>>(rw1, rw2, rw3, lw0, lw1, pw0, pw1,
                                  w_src0, w_dst0, w_src1, w_dst1, pk);
  k_node2<<<N_NODES/16, 256, 0, stream>>>(node_input, b_src0, b_dst0, pk,
                                          ns_src, ns_dst, nv_src, nv_dst);
  k_edge9<<<N_EDGES/EB, 256, 0, stream>>>(edge_attr, edge_scalars, edge_src, edge_dst,
                                          ns_src,ns_dst,nv_src,nv_dst,
                                          rb1,rb2,rb3,lb0,alpha_dot,pk,
                                          galpha,gval,gm1);
  k_agg2<<<N_NODES/16, 256, 0, stream>>>(edge_dst, galpha, gval, gm1, pb0, pk, out);
}